// Round 2
// baseline (719.955 us; speedup 1.0000x reference)
//
#include <hip/hip_runtime.h>
#include <math.h>

#define BB 32
#define HH 512
#define WW 512
#define NB 4096                      // 64*64 blocks per image
#define NTILES (BB * NB)             // 131072 tiles
#define QD 25165824                  // 32*3*4096*64  (qdct elements)
#define PP 16777216                  // 32*512*512*2  (enc_qf elements)
#define TAILOFF (2 * (size_t)QD + 2 * (size_t)PP)  // 83886080

__constant__ int c_zz[64] = {
    0,1,8,16,9,2,3,10,17,24,32,25,18,11,4,5,12,19,26,33,40,48,41,34,27,20,13,6,
    7,14,21,28,35,42,49,56,57,50,43,36,29,22,15,23,30,37,44,51,58,59,52,45,38,31,
    39,46,53,60,61,54,47,55,62,63};

__constant__ float c_yq[64] = {
    16,11,10,16,24,40,51,61, 12,12,14,19,26,58,60,55, 14,13,16,24,40,57,69,56,
    14,17,22,29,51,87,80,62, 18,22,37,56,68,109,103,77, 24,36,55,64,81,104,113,92,
    49,64,78,87,103,121,120,101, 72,92,95,98,112,100,103,99};

__constant__ float c_cq[64] = {
    17,18,24,47,99,99,99,99, 18,21,26,66,99,99,99,99, 24,26,56,99,99,99,99,99,
    47,66,99,99,99,99,99,99, 99,99,99,99,99,99,99,99, 99,99,99,99,99,99,99,99,
    99,99,99,99,99,99,99,99, 99,99,99,99,99,99,99,99};

__device__ __forceinline__ double qf_from_rank(double r) {
    double q = rint(2.0 + r * 48.0 + 0.0);     // QF_MIN + r*(QF_MAX-QF_MIN) + QF_BIAS
    return fmin(fmax(q, 2.0), 50.0);
}
__device__ __forceinline__ double scale_from_qf(double qf) {
    double s = (qf < 50.0) ? (5000.0 / qf) : (200.0 - 2.0 * qf);
    return rint(s) / 100.0;
}

// One-time (per launch) DCT-matrix build: double cos, cast to fp32 (matching
// the reference's jnp.asarray(_C, float32)), stored widened back to double.
__global__ void k_init(double* __restrict__ Cd) {
    int k = threadIdx.x >> 3, nn = threadIdx.x & 7;
    double v = 0.5 * cos((2.0 * nn + 1.0) * (double)k * M_PI / 16.0);
    if (k == 0) v *= 0.70710678118654752440;
    Cd[threadIdx.x] = (double)(float)v;
}

// LDS-free rounded-YCbCr + 2D DCT for one 8x8 tile per wave.
// Matrix rows live in registers; transposes go through __shfl (ds_bpermute:
// no bank conflicts, no barriers). Identical arithmetic to round 1
// (fp32-cast matrix entries, double accumulation, double rint).
__device__ __forceinline__ void dct3_shfl(const float* __restrict__ rgb, int gt,
                                          int lane, const double* __restrict__ Cd,
                                          double d3[3]) {
    int b = gt >> 12, n = gt & 4095;
    int i = n >> 6, j = n & 63;
    int r = lane >> 3, s = lane & 7;
    double Cv[8], Cu[8];
    #pragma unroll
    for (int t = 0; t < 8; ++t) { Cv[t] = Cd[s * 8 + t]; Cu[t] = Cd[r * 8 + t]; }
    int pix = ((b * HH + i * 8 + r) * WW + (j * 8 + s)) * 3;
    double R = rgb[pix], G = rgb[pix + 1], Bv = rgb[pix + 2];
    double X[3];
    X[0] = rint(R * (double)0.299f     + G * (double)0.587f     + Bv * (double)0.114f)             - 128.0;
    X[1] = rint(R * (double)-0.168736f + G * (double)-0.331264f + Bv * (double)0.5f       + 128.0) - 128.0;
    X[2] = rint(R * (double)0.5f       + G * (double)-0.418688f + Bv * (double)-0.081312f + 128.0) - 128.0;
    int rowbase = lane & 56;
    #pragma unroll
    for (int ch = 0; ch < 3; ++ch) {
        // pass 1: T[r][v] = sum_ss X[r][ss] * C[v][ss]   (lane holds v = s)
        double t = 0.0;
        #pragma unroll
        for (int ss = 0; ss < 8; ++ss)
            t += __shfl(X[ch], rowbase + ss, 64) * Cv[ss];
        // pass 2: d[u][v] = sum_rr C[u][rr] * T[rr][v]   (lane holds u = r)
        double d = 0.0;
        #pragma unroll
        for (int rr = 0; rr < 8; ++rr)
            d += __shfl(t, rr * 8 + s, 64) * Cu[rr];
        d3[ch] = d;
    }
}

__global__ __launch_bounds__(256) void k_energy(const float* __restrict__ rgb,
                                                const double* __restrict__ Cd,
                                                double* __restrict__ ey,
                                                double* __restrict__ ec) {
    int tid = threadIdx.x, lane = tid & 63;
    int gt = blockIdx.x * 4 + (tid >> 6);
    double d3[3];
    dct3_shfl(rgb, gt, lane, Cd, d3);
    double e[3];
    #pragma unroll
    for (int ch = 0; ch < 3; ++ch) {
        double v = d3[ch] * d3[ch];
        #pragma unroll
        for (int off = 1; off < 64; off <<= 1) v += __shfl_xor(v, off);
        double dc = __shfl(d3[ch], 0, 64);
        e[ch] = log1p(v - dc * dc + 1e-6);
    }
    if (lane == 0) {
        ey[gt] = e[0];
        ec[gt] = 0.5 * (e[1] + e[2]);
    }
}

__global__ __launch_bounds__(256) void k_minmax(const double* __restrict__ ey,
                                                const double* __restrict__ ec,
                                                double* __restrict__ mm,
                                                float* __restrict__ out_tail) {
    __shared__ double s0[256], s1[256], s2[256], s3[256];
    int b = blockIdx.x, tid = threadIdx.x;
    double mny = 1e300, mxy = -1e300, mnc = 1e300, mxc = -1e300;
    for (int n = tid; n < NB; n += 256) {
        double vy = ey[b * NB + n], vc = ec[b * NB + n];
        mny = fmin(mny, vy); mxy = fmax(mxy, vy);
        mnc = fmin(mnc, vc); mxc = fmax(mxc, vc);
    }
    s0[tid] = mny; s1[tid] = mxy; s2[tid] = mnc; s3[tid] = mxc;
    __syncthreads();
    for (int off = 128; off > 0; off >>= 1) {
        if (tid < off) {
            s0[tid] = fmin(s0[tid], s0[tid + off]);
            s1[tid] = fmax(s1[tid], s1[tid + off]);
            s2[tid] = fmin(s2[tid], s2[tid + off]);
            s3[tid] = fmax(s3[tid], s3[tid + off]);
        }
        __syncthreads();
    }
    if (tid == 0) {
        mm[b] = s0[0]; mm[32 + b] = s1[0]; mm[64 + b] = s2[0]; mm[96 + b] = s3[0];
        double ry = (s1[0] - s0[0]) / (s1[0] - s0[0] + 1e-6);
        double rc = (s3[0] - s2[0]) / (s3[0] - s2[0] + 1e-6);
        out_tail[b]      = (float)qf_from_rank(0.0);   // y_qf_min
        out_tail[32 + b] = (float)qf_from_rank(ry);    // y_qf_max
        out_tail[64 + b] = (float)qf_from_rank(0.0);   // c_qf_min
        out_tail[96 + b] = (float)qf_from_rank(rc);    // c_qf_max
    }
}

__global__ __launch_bounds__(256) void k_quant(const float* __restrict__ rgb,
                                               const double* __restrict__ Cd,
                                               const double* __restrict__ ey,
                                               const double* __restrict__ ec,
                                               const double* __restrict__ mm,
                                               float* __restrict__ out) {
    int tid = threadIdx.x, lane = tid & 63;
    int gt = blockIdx.x * 4 + (tid >> 6);
    double d3[3];
    dct3_shfl(rgb, gt, lane, Cd, d3);
    int b = gt >> 12, n = gt & 4095;
    int i = n >> 6, j = n & 63;
    int r = lane >> 3, s = lane & 7;

    double eyv = ey[gt], ecv = ec[gt];
    double mny = mm[b], mxy = mm[32 + b], mnc = mm[64 + b], mxc = mm[96 + b];
    double ry = (eyv - mny) / (mxy - mny + 1e-6);
    double rc = (ecv - mnc) / (mxc - mnc + 1e-6);
    double qy = qf_from_rank(ry), qc = qf_from_rank(rc);
    double sy = scale_from_qf(qy), sc = scale_from_qf(qc);

    int px = (b * HH + i * 8 + r) * WW + (j * 8 + s);
    ((float2*)(out + 2 * (size_t)QD))[px]      = make_float2((float)qy, (float)qc);
    ((float2*)(out + 2 * (size_t)QD + PP))[px] = make_float2((float)sy, (float)sc);

    size_t qbase = ((size_t)(b * 3) * NB + n) * 64 + lane;
    out[qbase]                        = (float)rint(d3[0] / (sy * (double)c_yq[lane]));
    out[qbase + (size_t)NB * 64]      = (float)rint(d3[1] / (sc * (double)c_cq[lane]));
    out[qbase + 2 * (size_t)NB * 64]  = (float)rint(d3[2] / (sc * (double)c_cq[lane]));
}

__global__ __launch_bounds__(256) void k_blocks(const float* __restrict__ out_q,
                                                float* __restrict__ out_b) {
    int tid = threadIdx.x;
    int gt = blockIdx.x * 4 + (tid >> 6);   // over BB*3*NB = 393216 (b,ch,n) rows
    int lane = tid & 63;
    int n = gt & 4095;
    int zz = c_zz[lane];
    size_t base = (size_t)gt * 64;
    float cur = out_q[base + zz];
    float delta = cur;
    if (n > 0) delta = cur - out_q[base - 64 + zz];
    // |delta| is a small integer -> log2f is ~1e-7 relative error, harmless
    out_b[base + lane] = log2f(fabsf(delta) + 1.0f);
}

extern "C" void kernel_launch(void* const* d_in, const int* in_sizes, int n_in,
                              void* d_out, int out_size, void* d_ws, size_t ws_size,
                              hipStream_t stream) {
    const float* rgb = (const float*)d_in[0];
    float* out = (float*)d_out;
    double* ws = (double*)d_ws;
    double* Cd = ws;                                   // 64 doubles
    double* ey = ws + 64;
    double* ec = ws + 64 + (size_t)NTILES;
    double* mm = ws + 64 + 2 * (size_t)NTILES;         // [mny|mxy|mnc|mxc] x 32

    dim3 blk(256);
    k_init<<<1, dim3(64), 0, stream>>>(Cd);
    k_energy<<<NTILES / 4, blk, 0, stream>>>(rgb, Cd, ey, ec);
    k_minmax<<<BB, blk, 0, stream>>>(ey, ec, mm, out + TAILOFF);
    k_quant<<<NTILES / 4, blk, 0, stream>>>(rgb, Cd, ey, ec, mm, out);
    k_blocks<<<(BB * 3 * NB) / 4, blk, 0, stream>>>(out, out + QD);
}

// Round 3
// 523.285 us; speedup vs baseline: 1.3758x; 1.3758x over previous
//
#include <hip/hip_runtime.h>
#include <math.h>

#define BB 32
#define HH 512
#define WW 512
#define NB 4096                      // 64*64 blocks per image
#define NTILES (BB * NB)             // 131072 blocks total
#define QD 25165824                  // 32*3*4096*64  (qdct elements)
#define PP 16777216                  // 32*512*512*2  (enc_qf elements)
#define TAILOFF (2 * (size_t)QD + 2 * (size_t)PP)  // 83886080

__constant__ int c_zz[64] = {
    0,1,8,16,9,2,3,10,17,24,32,25,18,11,4,5,12,19,26,33,40,48,41,34,27,20,13,6,
    7,14,21,28,35,42,49,56,57,50,43,36,29,22,15,23,30,37,44,51,58,59,52,45,38,31,
    39,46,53,60,61,54,47,55,62,63};

struct CdArg { double v[64]; };                            // fp32-cast DCT matrix, widened
struct QArg  { float Cf[64]; double rqY[64]; double rqC[64]; };

__device__ __forceinline__ double qf_from_rank(double r) {
    double q = rint(2.0 + r * 48.0 + 0.0);
    return fmin(fmax(q, 2.0), 50.0);
}
__device__ __forceinline__ double scale_from_qf(double qf) {
    double s = (qf < 50.0) ? (5000.0 / qf) : (200.0 - 2.0 * qf);
    return rint(s) / 100.0;
}

// Stage one block-row (8 pixel rows x 512 px) as rounded-YCbCr planar floats.
// Thread t handles 16 consecutive pixels. Identical rounding arithmetic to R1/R2.
__device__ __forceinline__ void stage_ycc(const float* __restrict__ rgb,
                                          int b, int i, int t,
                                          float (*planes)[8][512]) {
    const float* src = rgb + (size_t)(b * HH + i * 8) * WW * 3;
    int p0 = t * 16;
    alignas(16) float px[48];
    const float4* s4 = (const float4*)(src + (size_t)p0 * 3);
    #pragma unroll
    for (int k = 0; k < 12; ++k) ((float4*)px)[k] = s4[k];
    alignas(16) float yb[16], cb[16], cr[16];
    #pragma unroll
    for (int k = 0; k < 16; ++k) {
        double R = px[3 * k], G = px[3 * k + 1], Bv = px[3 * k + 2];
        yb[k] = (float)(rint(R * (double)0.299f     + G * (double)0.587f     + Bv * (double)0.114f)             - 128.0);
        cb[k] = (float)(rint(R * (double)-0.168736f + G * (double)-0.331264f + Bv * (double)0.5f       + 128.0) - 128.0);
        cr[k] = (float)(rint(R * (double)0.5f       + G * (double)-0.418688f + Bv * (double)-0.081312f + 128.0) - 128.0);
    }
    int r0 = p0 >> 9, c0 = p0 & 511;
    #pragma unroll
    for (int k = 0; k < 4; ++k) {
        *(float4*)&planes[0][r0][c0 + 4 * k] = ((float4*)yb)[k];
        *(float4*)&planes[1][r0][c0 + 4 * k] = ((float4*)cb)[k];
        *(float4*)&planes[2][r0][c0 + 4 * k] = ((float4*)cr)[k];
    }
}

// Thread-per-(block,channel) fp64 DCT -> AC energy. No cross-lane traffic.
__global__ __launch_bounds__(256, 2) void k_energy(const float* __restrict__ rgb,
                                                   CdArg A,
                                                   double* __restrict__ ey,
                                                   double* __restrict__ ec) {
    __shared__ __align__(16) float planes[3][8][512];
    __shared__ double ecomb[2][64];
    int b = blockIdx.x >> 6, i = blockIdx.x & 63;
    int t = threadIdx.x;
    stage_ycc(rgb, b, i, t, planes);
    __syncthreads();
    int ch = t >> 6, j = t & 63;
    if (ch < 3) {
        double U[8][8];
        #pragma unroll
        for (int r = 0; r < 8; ++r) {
            alignas(16) float xr[8];
            *(float4*)xr       = *(const float4*)&planes[ch][r][j * 8];
            *(float4*)(xr + 4) = *(const float4*)&planes[ch][r][j * 8 + 4];
            double xd[8];
            #pragma unroll
            for (int s = 0; s < 8; ++s) xd[s] = (double)xr[s];
            #pragma unroll
            for (int v = 0; v < 8; ++v) {
                double u = 0.0;
                #pragma unroll
                for (int s = 0; s < 8; ++s) u += xd[s] * A.v[v * 8 + s];
                U[r][v] = u;
            }
        }
        double sum = 0.0, dc = 0.0;
        #pragma unroll
        for (int u = 0; u < 8; ++u) {
            #pragma unroll
            for (int v = 0; v < 8; ++v) {
                double d = 0.0;
                #pragma unroll
                for (int r = 0; r < 8; ++r) d += A.v[u * 8 + r] * U[r][v];
                sum += d * d;
                if (u == 0 && v == 0) dc = d;
            }
        }
        double e = log1p(sum - dc * dc + 1e-6);
        if (ch == 0) ey[b * NB + i * 64 + j] = e;
        else ecomb[ch - 1][j] = e;
    }
    __syncthreads();
    if (t < 64) ec[b * NB + i * 64 + t] = 0.5 * (ecomb[0][t] + ecomb[1][t]);
}

__global__ __launch_bounds__(256) void k_minmax(const double* __restrict__ ey,
                                                const double* __restrict__ ec,
                                                double* __restrict__ mm,
                                                float* __restrict__ out_tail) {
    __shared__ double s0[256], s1[256], s2[256], s3[256];
    int b = blockIdx.x, tid = threadIdx.x;
    double mny = 1e300, mxy = -1e300, mnc = 1e300, mxc = -1e300;
    for (int n = tid; n < NB; n += 256) {
        double vy = ey[b * NB + n], vc = ec[b * NB + n];
        mny = fmin(mny, vy); mxy = fmax(mxy, vy);
        mnc = fmin(mnc, vc); mxc = fmax(mxc, vc);
    }
    s0[tid] = mny; s1[tid] = mxy; s2[tid] = mnc; s3[tid] = mxc;
    __syncthreads();
    for (int off = 128; off > 0; off >>= 1) {
        if (tid < off) {
            s0[tid] = fmin(s0[tid], s0[tid + off]);
            s1[tid] = fmax(s1[tid], s1[tid + off]);
            s2[tid] = fmin(s2[tid], s2[tid + off]);
            s3[tid] = fmax(s3[tid], s3[tid + off]);
        }
        __syncthreads();
    }
    if (tid == 0) {
        mm[b] = s0[0]; mm[32 + b] = s1[0]; mm[64 + b] = s2[0]; mm[96 + b] = s3[0];
        double ry = (s1[0] - s0[0]) / (s1[0] - s0[0] + 1e-6);
        double rc = (s3[0] - s2[0]) / (s3[0] - s2[0] + 1e-6);
        out_tail[b]      = (float)qf_from_rank(0.0);
        out_tail[32 + b] = (float)qf_from_rank(ry);
        out_tail[64 + b] = (float)qf_from_rank(0.0);
        out_tail[96 + b] = (float)qf_from_rank(rc);
    }
}

// Thread-per-(block,channel) fp32 DCT (errors land in the tolerated +-1 rint
// class), fp64 decision math (rank/QF/scale), reciprocal-mul quantizer.
__global__ __launch_bounds__(256, 2) void k_quant(const float* __restrict__ rgb,
                                                  QArg A,
                                                  const double* __restrict__ ey,
                                                  const double* __restrict__ ec,
                                                  const double* __restrict__ mm,
                                                  float* __restrict__ out) {
    __shared__ __align__(16) float planes[3][8][512];
    int b = blockIdx.x >> 6, i = blockIdx.x & 63;
    int t = threadIdx.x;
    stage_ycc(rgb, b, i, t, planes);
    __syncthreads();
    int ch = t >> 6, j = t & 63;
    if (ch < 3) {
        int gt = b * NB + i * 64 + j;
        double eyv = ey[gt], ecv = ec[gt];
        double mny = mm[b], mxy = mm[32 + b], mnc = mm[64 + b], mxc = mm[96 + b];
        double ry = (eyv - mny) / (mxy - mny + 1e-6);
        double rc = (ecv - mnc) / (mxc - mnc + 1e-6);
        double qy = qf_from_rank(ry), qc = qf_from_rank(rc);
        double sy = scale_from_qf(qy), sc = scale_from_qf(qc);

        float U[8][8];
        #pragma unroll
        for (int r = 0; r < 8; ++r) {
            alignas(16) float xr[8];
            *(float4*)xr       = *(const float4*)&planes[ch][r][j * 8];
            *(float4*)(xr + 4) = *(const float4*)&planes[ch][r][j * 8 + 4];
            #pragma unroll
            for (int v = 0; v < 8; ++v) {
                float u = 0.0f;
                #pragma unroll
                for (int s = 0; s < 8; ++s) u += xr[s] * A.Cf[v * 8 + s];
                U[r][v] = u;
            }
        }
        double rinv = 1.0 / ((ch == 0) ? sy : sc);
        const double* rqt = (ch == 0) ? A.rqY : A.rqC;
        size_t qbase = (((size_t)b * 3 + ch) * NB + (size_t)(i * 64 + j)) * 64;
        #pragma unroll
        for (int u = 0; u < 8; ++u) {
            alignas(16) float orow[8];
            #pragma unroll
            for (int v = 0; v < 8; ++v) {
                float d = 0.0f;
                #pragma unroll
                for (int r = 0; r < 8; ++r) d += A.Cf[u * 8 + r] * U[r][v];
                orow[v] = (float)rint((double)d * (rqt[u * 8 + v] * rinv));
            }
            *(float4*)(out + qbase + u * 8)     = ((float4*)orow)[0];
            *(float4*)(out + qbase + u * 8 + 4) = ((float4*)orow)[1];
        }

        // pixel maps: wave0 writes enc_qf, wave1 writes enc_scale
        if (ch < 2) {
            float4 v4 = (ch == 0)
                ? make_float4((float)qy, (float)qc, (float)qy, (float)qc)
                : make_float4((float)sy, (float)sc, (float)sy, (float)sc);
            float* mbase = out + 2 * (size_t)QD + (ch ? PP : 0);
            size_t P = (size_t)(b * HH + i * 8) * WW + j * 8;   // in float2 units
            #pragma unroll
            for (int rr = 0; rr < 8; ++rr) {
                float4* dst = (float4*)((float2*)mbase + P + (size_t)rr * WW);
                dst[0] = v4; dst[1] = v4; dst[2] = v4; dst[3] = v4;
            }
        }
    }
}

// delta (natural order, coalesced) -> zigzag via one fp32 shuffle -> log2
__global__ __launch_bounds__(256) void k_blocks(const float* __restrict__ q,
                                                float* __restrict__ ob) {
    int t = threadIdx.x;
    int row = blockIdx.x * 4 + (t >> 6);   // (b,ch,n) among 393216 rows
    int lane = t & 63;
    int n = row & 4095;
    size_t base = (size_t)row * 64;
    float cur = q[base + lane];
    float prev = (n > 0) ? q[base - 64 + lane] : 0.0f;
    float dlt = cur - prev;
    float g = __shfl(dlt, c_zz[lane], 64);
    ob[base + lane] = log2f(fabsf(g) + 1.0f);
}

extern "C" void kernel_launch(void* const* d_in, const int* in_sizes, int n_in,
                              void* d_out, int out_size, void* d_ws, size_t ws_size,
                              hipStream_t stream) {
    const float* rgb = (const float*)d_in[0];
    float* out = (float*)d_out;
    double* ws = (double*)d_ws;
    double* ey = ws;
    double* ec = ws + (size_t)NTILES;
    double* mm = ws + 2 * (size_t)NTILES;

    static const double YQ[64] = {
        16,11,10,16,24,40,51,61, 12,12,14,19,26,58,60,55, 14,13,16,24,40,57,69,56,
        14,17,22,29,51,87,80,62, 18,22,37,56,68,109,103,77, 24,36,55,64,81,104,113,92,
        49,64,78,87,103,121,120,101, 72,92,95,98,112,100,103,99};
    static const double CQ[64] = {
        17,18,24,47,99,99,99,99, 18,21,26,66,99,99,99,99, 24,26,56,99,99,99,99,99,
        47,66,99,99,99,99,99,99, 99,99,99,99,99,99,99,99, 99,99,99,99,99,99,99,99,
        99,99,99,99,99,99,99,99, 99,99,99,99,99,99,99,99};

    CdArg ca; QArg qa;
    for (int k = 0; k < 8; ++k)
        for (int n = 0; n < 8; ++n) {
            double v = 0.5 * cos((2.0 * n + 1.0) * (double)k * M_PI / 16.0);
            if (k == 0) v *= 0.70710678118654752440;
            float f = (float)v;                 // reference casts DCT_M to fp32
            ca.v[k * 8 + n] = (double)f;
            qa.Cf[k * 8 + n] = f;
        }
    for (int k = 0; k < 64; ++k) { qa.rqY[k] = 1.0 / YQ[k]; qa.rqC[k] = 1.0 / CQ[k]; }

    dim3 blk(256);
    k_energy<<<BB * 64, blk, 0, stream>>>(rgb, ca, ey, ec);
    k_minmax<<<BB, blk, 0, stream>>>(ey, ec, mm, out + TAILOFF);
    k_quant<<<BB * 64, blk, 0, stream>>>(rgb, qa, ey, ec, mm, out);
    k_blocks<<<(BB * 3 * NB) / 4, blk, 0, stream>>>(out, out + QD);
}

// Round 4
// 499.200 us; speedup vs baseline: 1.4422x; 1.0482x over previous
//
#include <hip/hip_runtime.h>
#include <math.h>

#define BB 32
#define HH 512
#define WW 512
#define NB 4096                      // 64*64 blocks per image
#define QD 25165824                  // 32*3*4096*64  (qdct elements)
#define PP 16777216                  // 32*512*512*2  (enc_qf elements)
#define TAILOFF (2 * (size_t)QD + 2 * (size_t)PP)  // 83886080

// compile-time zigzag (folds to literal indices in fully-unrolled loops)
constexpr int ZZc[64] = {
    0,1,8,16,9,2,3,10,17,24,32,25,18,11,4,5,12,19,26,33,40,48,41,34,27,20,13,6,
    7,14,21,28,35,42,49,56,57,50,43,36,29,22,15,23,30,37,44,51,58,59,52,45,38,31,
    39,46,53,60,61,54,47,55,62,63};
__constant__ int c_zz[64] = {
    0,1,8,16,9,2,3,10,17,24,32,25,18,11,4,5,12,19,26,33,40,48,41,34,27,20,13,6,
    7,14,21,28,35,42,49,56,57,50,43,36,29,22,15,23,30,37,44,51,58,59,52,45,38,31,
    39,46,53,60,61,54,47,55,62,63};

struct QArg { float Cf[64]; double rqY[64]; double rqC[64]; };

__device__ __forceinline__ double qf_from_rank(double r) {
    double q = rint(2.0 + r * 48.0 + 0.0);
    return fmin(fmax(q, 2.0), 50.0);
}
__device__ __forceinline__ double scale_from_qf(double qf) {
    double s = (qf < 50.0) ? (5000.0 / qf) : (200.0 - 2.0 * qf);
    return rint(s) / 100.0;
}

// Rounded YCbCr for 16 consecutive px of one row; identical fp64 rint math to R1-R3.
__device__ __forceinline__ void ycc16(const float* __restrict__ src, int p0,
                                      int* y, int* cb, int* cr) {
    float px[48];
    const float4* s4 = (const float4*)(src + (size_t)p0 * 3);
    #pragma unroll
    for (int k = 0; k < 12; ++k) ((float4*)px)[k] = s4[k];
    #pragma unroll
    for (int k = 0; k < 16; ++k) {
        double R = px[3 * k], G = px[3 * k + 1], Bv = px[3 * k + 2];
        y[k]  = (int)(rint(R * (double)0.299f     + G * (double)0.587f     + Bv * (double)0.114f)             - 128.0);
        cb[k] = (int)(rint(R * (double)-0.168736f + G * (double)-0.331264f + Bv * (double)0.5f       + 128.0) - 128.0);
        cr[k] = (int)(rint(R * (double)0.5f       + G * (double)-0.418688f + Bv * (double)-0.081312f + 128.0) - 128.0);
    }
}

// Energy via Parseval: sum d^2 == sum x^2 (orthonormal DCT), d00 == sum(x)/8.
// x are integers in [-128,127] -> int32-exact sums, fp64-exact energy.
__global__ __launch_bounds__(256, 4) void k_energy(const float* __restrict__ rgb,
                                                   double* __restrict__ ey,
                                                   double* __restrict__ ec) {
    __shared__ int4 part[3][8][32];     // {sumA, sqA, sumB, sqB} per (ch,row,blockpair)
    __shared__ double ecomb[2][64];
    int b = blockIdx.x >> 6, i = blockIdx.x & 63, t = threadIdx.x;
    const float* src = rgb + (size_t)(b * HH + i * 8) * WW * 3;
    {
        int y[16], cb[16], cr[16];
        ycc16(src, t * 16, y, cb, cr);
        int s[3][2] = {{0,0},{0,0},{0,0}}, s2[3][2] = {{0,0},{0,0},{0,0}};
        #pragma unroll
        for (int k = 0; k < 16; ++k) {
            int h = k >> 3;
            s[0][h] += y[k];  s2[0][h] += y[k] * y[k];
            s[1][h] += cb[k]; s2[1][h] += cb[k] * cb[k];
            s[2][h] += cr[k]; s2[2][h] += cr[k] * cr[k];
        }
        int r0 = t >> 5, c = t & 31;
        #pragma unroll
        for (int ch = 0; ch < 3; ++ch)
            part[ch][r0][c] = make_int4(s[ch][0], s2[ch][0], s[ch][1], s2[ch][1]);
    }
    __syncthreads();
    int ch = t >> 6, j = t & 63;
    if (ch < 3) {
        int S = 0, S2 = 0;
        #pragma unroll
        for (int r = 0; r < 8; ++r) {
            const int2* p = (const int2*)&part[ch][r][j >> 1];
            int2 v = p[j & 1];
            S += v.x; S2 += v.y;
        }
        double e = log1p((double)S2 - (double)S * (double)S * (1.0 / 64.0) + 1e-6);
        if (ch == 0) ey[b * NB + i * 64 + j] = e;
        else ecomb[ch - 1][j] = e;
    }
    __syncthreads();
    if (t < 64) ec[b * NB + i * 64 + t] = 0.5 * (ecomb[0][t] + ecomb[1][t]);
}

__global__ __launch_bounds__(256) void k_minmax(const double* __restrict__ ey,
                                                const double* __restrict__ ec,
                                                double* __restrict__ mm,
                                                float* __restrict__ out_tail) {
    __shared__ double s0[256], s1[256], s2[256], s3[256];
    int b = blockIdx.x, tid = threadIdx.x;
    double mny = 1e300, mxy = -1e300, mnc = 1e300, mxc = -1e300;
    for (int n = tid; n < NB; n += 256) {
        double vy = ey[b * NB + n], vc = ec[b * NB + n];
        mny = fmin(mny, vy); mxy = fmax(mxy, vy);
        mnc = fmin(mnc, vc); mxc = fmax(mxc, vc);
    }
    s0[tid] = mny; s1[tid] = mxy; s2[tid] = mnc; s3[tid] = mxc;
    __syncthreads();
    for (int off = 128; off > 0; off >>= 1) {
        if (tid < off) {
            s0[tid] = fmin(s0[tid], s0[tid + off]);
            s1[tid] = fmax(s1[tid], s1[tid + off]);
            s2[tid] = fmin(s2[tid], s2[tid + off]);
            s3[tid] = fmax(s3[tid], s3[tid + off]);
        }
        __syncthreads();
    }
    if (tid == 0) {
        mm[b] = s0[0]; mm[32 + b] = s1[0]; mm[64 + b] = s2[0]; mm[96 + b] = s3[0];
        double ry = (s1[0] - s0[0]) / (s1[0] - s0[0] + 1e-6);
        double rc = (s3[0] - s2[0]) / (s3[0] - s2[0] + 1e-6);
        out_tail[b]      = (float)qf_from_rank(0.0);
        out_tail[32 + b] = (float)qf_from_rank(ry);
        out_tail[64 + b] = (float)qf_from_rank(0.0);
        out_tail[96 + b] = (float)qf_from_rank(rc);
    }
}

// int16 LDS staging (dense, conflict-free) -> fp32 DCT -> quantize -> fused
// delta/zigzag/log2 via short LDS round-trip (stride 66 -> 2-way, free).
__global__ __launch_bounds__(256, 4) void k_quant(const float* __restrict__ rgb,
                                                  QArg A,
                                                  const double* __restrict__ ey,
                                                  const double* __restrict__ ec,
                                                  const double* __restrict__ mm,
                                                  float* __restrict__ out) {
    __shared__ __align__(16) short sm[13056];   // planes [3][8][512], reused as sq[192][66]
    int b = blockIdx.x >> 6, i = blockIdx.x & 63, t = threadIdx.x;
    {
        int y[16], cb[16], cr[16];
        ycc16(rgb + (size_t)(b * HH + i * 8) * WW * 3, t * 16, y, cb, cr);
        alignas(16) short yb[16], cbb[16], crb[16];
        #pragma unroll
        for (int k = 0; k < 16; ++k) {
            yb[k] = (short)y[k]; cbb[k] = (short)cb[k]; crb[k] = (short)cr[k];
        }
        int4* d0 = (int4*)&sm[0 * 4096 + 16 * t];
        int4* d1 = (int4*)&sm[1 * 4096 + 16 * t];
        int4* d2 = (int4*)&sm[2 * 4096 + 16 * t];
        d0[0] = ((int4*)yb)[0];  d0[1] = ((int4*)yb)[1];
        d1[0] = ((int4*)cbb)[0]; d1[1] = ((int4*)cbb)[1];
        d2[0] = ((int4*)crb)[0]; d2[1] = ((int4*)crb)[1];
    }
    __syncthreads();
    int ch = t >> 6, j = t & 63;
    float U[8][8];
    double qy = 0, qc = 0, sy = 1, sc = 1;
    if (ch < 3) {
        int gt = b * NB + i * 64 + j;
        double eyv = ey[gt], ecv = ec[gt];
        double mny = mm[b], mxy = mm[32 + b], mnc = mm[64 + b], mxc = mm[96 + b];
        double ry = (eyv - mny) / (mxy - mny + 1e-6);
        double rc = (ecv - mnc) / (mxc - mnc + 1e-6);
        qy = qf_from_rank(ry); qc = qf_from_rank(rc);
        sy = scale_from_qf(qy); sc = scale_from_qf(qc);
        #pragma unroll
        for (int r = 0; r < 8; ++r) {
            alignas(16) short xs[8];
            *(int4*)xs = *(const int4*)&sm[ch * 4096 + r * 512 + j * 8];
            float xr[8];
            #pragma unroll
            for (int s = 0; s < 8; ++s) xr[s] = (float)xs[s];
            #pragma unroll
            for (int v = 0; v < 8; ++v) {
                float u = 0.0f;
                #pragma unroll
                for (int s = 0; s < 8; ++s) u += xr[s] * A.Cf[v * 8 + s];
                U[r][v] = u;
            }
        }
    }
    __syncthreads();                    // plane reads done; reuse sm as sq
    if (ch < 3) {
        double rinv = 1.0 / ((ch == 0) ? sy : sc);
        const double* rqt = (ch == 0) ? A.rqY : A.rqC;
        size_t qbase = (((size_t)b * 3 + ch) * NB + (size_t)(i * 64 + j)) * 64;
        int sqb = (ch * 64 + j) * 66;
        #pragma unroll
        for (int u = 0; u < 8; ++u) {
            alignas(16) float orow[8];
            alignas(4) short srow[8];
            #pragma unroll
            for (int v = 0; v < 8; ++v) {
                float d = 0.0f;
                #pragma unroll
                for (int r = 0; r < 8; ++r) d += A.Cf[u * 8 + r] * U[r][v];
                float qv = (float)rint((double)d * (rqt[u * 8 + v] * rinv));
                orow[v] = qv; srow[v] = (short)qv;
            }
            *(float4*)(out + qbase + u * 8)     = ((float4*)orow)[0];
            *(float4*)(out + qbase + u * 8 + 4) = ((float4*)orow)[1];
            short2* sd = (short2*)&sm[sqb + u * 8];
            sd[0] = ((short2*)srow)[0]; sd[1] = ((short2*)srow)[1];
            sd[2] = ((short2*)srow)[2]; sd[3] = ((short2*)srow)[3];
        }
    }
    __syncthreads();                    // all sq written
    if (ch < 3) {
        int sqb = (ch * 64 + j) * 66;
        size_t bbase = (size_t)QD + (((size_t)b * 3 + ch) * NB + (size_t)(i * 64 + j)) * 64;
        #pragma unroll
        for (int u = 0; u < 8; ++u) {
            alignas(16) float bo[8];
            #pragma unroll
            for (int e = 0; e < 8; ++e) {
                int zk = ZZc[u * 8 + e];                 // compile-time constant
                float cur = (float)sm[sqb + zk];
                float prv = (j > 0) ? (float)sm[sqb - 66 + zk] : 0.0f;
                bo[e] = log2f(fabsf(cur - prv) + 1.0f);  // j==0 fixed by k_fix
            }
            *(float4*)(out + bbase + u * 8)     = ((float4*)bo)[0];
            *(float4*)(out + bbase + u * 8 + 4) = ((float4*)bo)[1];
        }
        if (ch < 2) {
            float4 v4 = (ch == 0)
                ? make_float4((float)qy, (float)qc, (float)qy, (float)qc)
                : make_float4((float)sy, (float)sc, (float)sy, (float)sc);
            float* mbase = out + 2 * (size_t)QD + (ch ? PP : 0);
            size_t P = (size_t)(b * HH + i * 8) * WW + j * 8;   // float2 units
            #pragma unroll
            for (int rr = 0; rr < 8; ++rr) {
                float4* dst = (float4*)((float2*)mbase + P + (size_t)rr * WW);
                dst[0] = v4; dst[1] = v4; dst[2] = v4; dst[3] = v4;
            }
        }
    }
}

// Repair blocks-output rows where j==0 (needs previous block-row's qdct).
__global__ __launch_bounds__(256) void k_fix(const float* __restrict__ q,
                                             float* __restrict__ ob) {
    int idx = blockIdx.x * 256 + threadIdx.x;   // 32*3*64*64 = 393216
    int rid = idx >> 6, k = idx & 63;
    int bch = rid >> 6;                          // b*3+ch
    int i = rid & 63;
    size_t base = ((size_t)bch * NB + (size_t)i * 64) * 64;
    float cur = q[base + c_zz[k]];
    float prv = (i > 0) ? q[base - 64 + c_zz[k]] : 0.0f;
    ob[base + k] = log2f(fabsf(cur - prv) + 1.0f);
}

extern "C" void kernel_launch(void* const* d_in, const int* in_sizes, int n_in,
                              void* d_out, int out_size, void* d_ws, size_t ws_size,
                              hipStream_t stream) {
    const float* rgb = (const float*)d_in[0];
    float* out = (float*)d_out;
    double* ws = (double*)d_ws;
    double* ey = ws;
    double* ec = ws + (size_t)BB * NB;
    double* mm = ws + 2 * (size_t)BB * NB;

    static const double YQ[64] = {
        16,11,10,16,24,40,51,61, 12,12,14,19,26,58,60,55, 14,13,16,24,40,57,69,56,
        14,17,22,29,51,87,80,62, 18,22,37,56,68,109,103,77, 24,36,55,64,81,104,113,92,
        49,64,78,87,103,121,120,101, 72,92,95,98,112,100,103,99};
    static const double CQ[64] = {
        17,18,24,47,99,99,99,99, 18,21,26,66,99,99,99,99, 24,26,56,99,99,99,99,99,
        47,66,99,99,99,99,99,99, 99,99,99,99,99,99,99,99, 99,99,99,99,99,99,99,99,
        99,99,99,99,99,99,99,99, 99,99,99,99,99,99,99,99};

    QArg qa;
    for (int k = 0; k < 8; ++k)
        for (int n = 0; n < 8; ++n) {
            double v = 0.5 * cos((2.0 * n + 1.0) * (double)k * M_PI / 16.0);
            if (k == 0) v *= 0.70710678118654752440;
            qa.Cf[k * 8 + n] = (float)v;          // reference casts DCT_M to fp32
        }
    for (int k = 0; k < 64; ++k) { qa.rqY[k] = 1.0 / YQ[k]; qa.rqC[k] = 1.0 / CQ[k]; }

    dim3 blk(256);
    k_energy<<<BB * 64, blk, 0, stream>>>(rgb, ey, ec);
    k_minmax<<<BB, blk, 0, stream>>>(ey, ec, mm, out + TAILOFF);
    k_quant<<<BB * 64, blk, 0, stream>>>(rgb, qa, ey, ec, mm, out);
    k_fix<<<(BB * 3 * 64 * 64) / 256, blk, 0, stream>>>(out, out + QD);
}